// Round 3
// baseline (140.034 us; speedup 1.0000x reference)
//
#include <hip/hip_runtime.h>
#include <hip/hip_bf16.h>

#define B_ 2
#define S_ 2048
#define H_ 16
#define HD 64
#define R_ 1024
#define N_ (B_*S_)   // 4096 rows

typedef unsigned short ushort_t;
typedef short bf16x8 __attribute__((ext_vector_type(8)));
typedef float f32x4 __attribute__((ext_vector_type(4)));
typedef float f32x16 __attribute__((ext_vector_type(16)));

#define MFMA(a,b,c) __builtin_amdgcn_mfma_f32_16x16x32_bf16(a,b,c,0,0,0)
#define MFMA32(a,b,c) __builtin_amdgcn_mfma_f32_32x32x16_bf16(a,b,c,0,0,0)
#define GLD16(g,l) __builtin_amdgcn_global_load_lds( \
    (const __attribute__((address_space(1))) void*)(g), \
    (__attribute__((address_space(3))) void*)(l), 16, 0, 0)

__device__ __forceinline__ unsigned short f2bf(float f) {
  unsigned int u = __builtin_bit_cast(unsigned int, f);
  u += 0x7fffu + ((u >> 16) & 1u);   // RNE; inputs finite
  return (unsigned short)(u >> 16);
}

__device__ __forceinline__ unsigned int cvtpk(float lo, float hi) {
  unsigned int r;
  asm("v_cvt_pk_bf16_f32 %0, %1, %2" : "=v"(r) : "v"(lo), "v"(hi));
  return r;
}

__device__ __forceinline__ bf16x8 ld8(const ushort_t* p) {
  return *(const bf16x8*)p;
}

// ---------------- pre-pass: fp32 -> bf16 convert ----------------
__global__ __launch_bounds__(256) void k_convert_x(const float* __restrict__ x,
                                                   ushort_t* __restrict__ xb) {
  int i = blockIdx.x * 256 + threadIdx.x;      // 4 floats per thread
  float4 v = ((const float4*)x)[i];
  ushort4 o;
  o.x = f2bf(v.x); o.y = f2bf(v.y); o.z = f2bf(v.z); o.w = f2bf(v.w);
  ((ushort4*)xb)[i] = o;
}

// ---------- pre-pass: batched transpose fp32[rows][cols] -> bf16[cols][rows] ----------
__global__ __launch_bounds__(256) void k_transpose(const float* __restrict__ in,
                                                   ushort_t* __restrict__ out,
                                                   int rows, int cols) {
  __shared__ float t[64][65];
  const size_t bo = (size_t)blockIdx.z * rows * cols;
  const int r0 = blockIdx.x * 64, c0 = blockIdx.y * 64;
  const int tx = threadIdx.x & 63, ty = threadIdx.x >> 6;
  #pragma unroll
  for (int i = 0; i < 16; i++) {
    int r = ty * 16 + i;
    t[r][tx] = in[bo + (size_t)(r0 + r) * cols + c0 + tx];
  }
  __syncthreads();
  #pragma unroll
  for (int i = 0; i < 16; i++) {
    int c = ty * 16 + i;
    out[bo + (size_t)(c0 + c) * rows + r0 + tx] = f2bf(t[tx][c]);
  }
}

// ---------------- QKV projection GEMM ----------------
// block: 128 rows x 192 cols (one head), 4 waves in 2x2 (each 64x96)
// epilogue: Q scaled by log2(e)/8 (for exp2-softmax), K/Vt XOR-swizzled layouts.
__global__ __launch_bounds__(256, 2) void k_qkv(
    const ushort_t* __restrict__ Xb, const ushort_t* __restrict__ WT,
    const float* __restrict__ bqkv,
    ushort_t* __restrict__ Q, ushort_t* __restrict__ K, ushort_t* __restrict__ Vt) {
  __shared__ ushort_t lA[2][128 * 32];
  __shared__ ushort_t lB[2][192 * 32];
  const int m0 = blockIdx.x * 128;
  const int h  = blockIdx.y;
  const int tid = threadIdx.x;
  const int w = tid >> 6, l = tid & 63;
  const int lr = l & 15, lg = l >> 4;
  const int wr = w >> 1, wc = w & 1;

  const ushort_t* Asrc = Xb + (size_t)m0 * R_;
  const ushort_t* Bsrc = WT + (size_t)h * 192 * R_;
  const int arow = l >> 2;          // row within 16-row chunk
  const int acol = (l & 3) * 8;     // k element offset

  f32x4 acc[4][6];
  const f32x4 fz = {0.f, 0.f, 0.f, 0.f};
  #pragma unroll
  for (int m = 0; m < 4; m++)
    #pragma unroll
    for (int n = 0; n < 6; n++) acc[m][n] = fz;

  auto stage = [&](int buf, int kt) {
    const int k0 = kt * 32;
    #pragma unroll
    for (int i = 0; i < 2; i++) {     // A: 8 chunks of 1KB
      int chunk = w + 4 * i;
      GLD16(Asrc + (size_t)(chunk * 16 + arow) * R_ + k0 + acol, &lA[buf][chunk * 512]);
    }
    #pragma unroll
    for (int i = 0; i < 3; i++) {     // B: 12 chunks of 1KB
      int chunk = w + 4 * i;
      GLD16(Bsrc + (size_t)(chunk * 16 + arow) * R_ + k0 + acol, &lB[buf][chunk * 512]);
    }
  };

  stage(0, 0);
  asm volatile("s_waitcnt vmcnt(0)" ::: "memory");
  __syncthreads();

  int cur = 0;
  for (int kt = 0; kt < 32; ++kt) {
    if (kt < 31) stage(cur ^ 1, kt + 1);
    bf16x8 af[4], bfr[6];
    #pragma unroll
    for (int m = 0; m < 4; m++)
      af[m] = ld8(&lA[cur][(wr * 64 + m * 16 + lr) * 32 + lg * 8]);
    #pragma unroll
    for (int n = 0; n < 6; n++)
      bfr[n] = ld8(&lB[cur][(wc * 96 + n * 16 + lr) * 32 + lg * 8]);
    __builtin_amdgcn_s_setprio(1);
    #pragma unroll
    for (int m = 0; m < 4; m++)
      #pragma unroll
      for (int n = 0; n < 6; n++)
        acc[m][n] = MFMA(af[m], bfr[n], acc[m][n]);
    __builtin_amdgcn_s_setprio(0);
    asm volatile("s_waitcnt vmcnt(0)" ::: "memory");
    __syncthreads();
    cur ^= 1;
  }

  // epilogue: col = wc*96 + n*16 + lr ; row = m0 + wr*64 + m*16 + lg*4 + r
  #pragma unroll
  for (int n = 0; n < 6; n++) {
    const int col = wc * 96 + n * 16 + lr;
    const float bias = bqkv[h * 192 + col];
    #pragma unroll
    for (int m = 0; m < 4; m++) {
      const int rb = m0 + wr * 64 + m * 16 + lg * 4;
      #pragma unroll
      for (int r = 0; r < 4; r++) {
        float v = acc[m][n][r] + bias;
        int srow = rb + r;
        int b = srow >> 11, s = srow & 2047;
        size_t bh = (size_t)b * H_ + h;
        if (col < 64) {
          // Q scaled by log2(e)/8 so attn uses exp2 directly
          Q[(bh * S_ + s) * HD + col] = f2bf(v * 0.1803368801111137f);
        } else if (col < 128) {
          // K: [bh][s][d ^ ((s&7)<<3)]  (XOR swizzle baked into global layout)
          int d = col - 64;
          K[(bh * S_ + s) * HD + (d ^ ((s & 7) << 3))] = f2bf(v);
        } else {
          // Vt: [bh][d][s ^ ((d&7)<<3)]
          int d = col - 128;
          Vt[(bh * HD + d) * S_ + (s ^ ((d & 7) << 3))] = f2bf(v);
        }
      }
    }
  }
}

// ---------------- flash attention: 32x32 MFMA, swapped QK^T, in-register softmax ----------------
// grid: (S/128, B*H). block 256 = 4 waves; wave owns 32 q rows.
// S^T = mfma32(K, Q): lane holds q col = l&31, kv rows (reg&3)+8*(reg>>2)+4*hi.
// exp2 (log2e folded into Q) -> cvt_pk bf16 pairs -> xor-32 lane exchange
// -> P A-fragments in-register. Row sums via ones-MFMA on identical P bits.
__global__ __launch_bounds__(256, 2) void k_attn(
    const ushort_t* __restrict__ Q, const ushort_t* __restrict__ K,
    const ushort_t* __restrict__ Vt, ushort_t* __restrict__ AO) {
  __shared__ ushort_t lK[2][64 * 64];
  __shared__ ushort_t lV[2][64 * 64];
  const int qt = blockIdx.x;
  const int bh = blockIdx.y;
  const int b = bh >> 4, h = bh & 15;
  const int tid = threadIdx.x, w = tid >> 6, l = tid & 63;
  const int lq = l & 31, hi = l >> 5;

  const ushort_t* Qb = Q + (size_t)bh * S_ * HD;
  const ushort_t* Kb = K + (size_t)bh * S_ * HD;
  const ushort_t* Vb = Vt + (size_t)bh * HD * S_;

  // Q as B-fragment: col q = lq, k elems d = kd*16 + hi*8 + {0..7}
  bf16x8 qf[4];
  {
    int qrow = qt * 128 + 32 * w + lq;
    #pragma unroll
    for (int kd = 0; kd < 4; kd++)
      qf[kd] = ld8(&Qb[(size_t)qrow * HD + kd * 16 + hi * 8]);
  }

  auto stage = [&](int buf, int t0) {
    #pragma unroll
    for (int i = 0; i < 2; i++) {
      int chunk = w + 4 * i;            // 0..7, 1KB each (8 rows of 128B)
      int r = chunk * 8 + (l >> 3);
      int c = (l & 7) * 8;
      GLD16(&Kb[(size_t)(t0 + r) * HD + c], &lK[buf][chunk * 512]);
      GLD16(&Vb[(size_t)r * S_ + t0 + c], &lV[buf][chunk * 512]);
    }
  };

  const f32x16 fz16 = {0};
  const bf16x8 onesv = {0x3F80, 0x3F80, 0x3F80, 0x3F80, 0x3F80, 0x3F80, 0x3F80, 0x3F80};
  f32x16 oacc[2];   // [d-block of 32]
  f32x16 ss;        // row sums (same C/D row mapping as oacc)
  oacc[0] = fz16; oacc[1] = fz16; ss = fz16;

  const int swz = (lq & 7) * 8;     // XOR de-swizzle for K/V LDS rows

  stage(0, 0);
  asm volatile("s_waitcnt vmcnt(0)" ::: "memory");
  __syncthreads();

  int cur = 0;
  for (int kt = 0; kt < 32; ++kt) {
    if (kt < 31) stage(cur ^ 1, (kt + 1) * 64);

    // QK^T swapped: sc[n] = S^T[kv = n*32 + rows][q = lq]
    f32x16 sc[2];
    sc[0] = fz16; sc[1] = fz16;
    __builtin_amdgcn_s_setprio(1);
    #pragma unroll
    for (int kd = 0; kd < 4; kd++) {
      bf16x8 ka0 = ld8(&lK[cur][(lq) * 64 + ((kd * 16 + hi * 8) ^ swz)]);
      bf16x8 ka1 = ld8(&lK[cur][(32 + lq) * 64 + ((kd * 16 + hi * 8) ^ swz)]);
      sc[0] = MFMA32(ka0, qf[kd], sc[0]);
      sc[1] = MFMA32(ka1, qf[kd], sc[1]);
    }
    __builtin_amdgcn_s_setprio(0);

    // exp2 + pack to bf16 pairs: pk[n][b2] = kv {8*b2+4*hi, +1}, pq = {+2, +3}
    unsigned int pk[2][4], pq[2][4], px[2][4], pxq[2][4];
    #pragma unroll
    for (int n = 0; n < 2; n++)
      #pragma unroll
      for (int b2 = 0; b2 < 4; b2++) {
        float e0 = exp2f(sc[n][4 * b2 + 0]);
        float e1 = exp2f(sc[n][4 * b2 + 1]);
        float e2 = exp2f(sc[n][4 * b2 + 2]);
        float e3 = exp2f(sc[n][4 * b2 + 3]);
        pk[n][b2] = cvtpk(e0, e1);
        pq[n][b2] = cvtpk(e2, e3);
      }
    // exchange halves: lane <-> lane^32
    #pragma unroll
    for (int n = 0; n < 2; n++)
      #pragma unroll
      for (int b2 = 0; b2 < 4; b2++) {
        px[n][b2]  = __shfl_xor((int)pk[n][b2], 32, 64);
        pxq[n][b2] = __shfl_xor((int)pq[n][b2], 32, 64);
      }

    // PV + row-sum: per k-slice ks (kv ks*16..+15), build P A-fragment in-register
    __builtin_amdgcn_s_setprio(1);
    #pragma unroll
    for (int ks = 0; ks < 4; ks++) {
      const int n = ks >> 1, k1 = (ks & 1) * 2;
      unsigned int w0 = hi ? px[n][k1 + 1]  : pk[n][k1];
      unsigned int w1 = hi ? pxq[n][k1 + 1] : pq[n][k1];
      unsigned int w2 = hi ? pk[n][k1 + 1]  : px[n][k1];
      unsigned int w3 = hi ? pq[n][k1 + 1]  : pxq[n][k1];
      int4 wv = {(int)w0, (int)w1, (int)w2, (int)w3};
      bf16x8 pa = __builtin_bit_cast(bf16x8, wv);
      ss = MFMA32(pa, onesv, ss);
      #pragma unroll
      for (int db = 0; db < 2; db++) {
        bf16x8 vb = ld8(&lV[cur][(db * 32 + lq) * 64 + ((ks * 16 + hi * 8) ^ swz)]);
        oacc[db] = MFMA32(pa, vb, oacc[db]);
      }
    }
    __builtin_amdgcn_s_setprio(0);

    asm volatile("s_waitcnt vmcnt(0)" ::: "memory");
    __syncthreads();
    cur ^= 1;
  }

  // epilogue: rows q = (reg&3)+8*(reg>>2)+4*hi ; col d = db*32+lq
  float inv[16];
  #pragma unroll
  for (int reg = 0; reg < 16; reg++) inv[reg] = 1.0f / ss[reg];
  #pragma unroll
  for (int db = 0; db < 2; db++)
    #pragma unroll
    for (int reg = 0; reg < 16; reg++) {
      int qloc = (reg & 3) + 8 * (reg >> 2) + 4 * hi;
      int s = qt * 128 + 32 * w + qloc;
      float o = oacc[db][reg] * inv[reg];
      AO[(size_t)(b * S_ + s) * R_ + h * HD + db * 32 + lq] = f2bf(o);
    }
}

// ---------------- output projection GEMM ----------------
// block: 128x128, 4 waves 2x2 (each 64x64). out fp32 + bias.
__global__ __launch_bounds__(256, 2) void k_out(
    const ushort_t* __restrict__ AO, const ushort_t* __restrict__ WoT,
    const float* __restrict__ bo, float* __restrict__ out) {
  __shared__ ushort_t lA[2][128 * 32];
  __shared__ ushort_t lB[2][128 * 32];
  const int m0 = blockIdx.x * 128, n0 = blockIdx.y * 128;
  const int tid = threadIdx.x, w = tid >> 6, l = tid & 63;
  const int lr = l & 15, lg = l >> 4;
  const int wr = w >> 1, wc = w & 1;
  const ushort_t* Asrc = AO + (size_t)m0 * R_;
  const ushort_t* Bsrc = WoT + (size_t)n0 * R_;
  const int arow = l >> 2, acol = (l & 3) * 8;

  f32x4 acc[4][4];
  const f32x4 fz = {0.f, 0.f, 0.f, 0.f};
  #pragma unroll
  for (int m = 0; m < 4; m++)
    #pragma unroll
    for (int n = 0; n < 4; n++) acc[m][n] = fz;

  auto stage = [&](int buf, int kt) {
    const int k0 = kt * 32;
    #pragma unroll
    for (int i = 0; i < 2; i++) {
      int chunk = w + 4 * i;
      GLD16(Asrc + (size_t)(chunk * 16 + arow) * R_ + k0 + acol, &lA[buf][chunk * 512]);
      GLD16(Bsrc + (size_t)(chunk * 16 + arow) * R_ + k0 + acol, &lB[buf][chunk * 512]);
    }
  };

  stage(0, 0);
  asm volatile("s_waitcnt vmcnt(0)" ::: "memory");
  __syncthreads();

  int cur = 0;
  for (int kt = 0; kt < 32; ++kt) {
    if (kt < 31) stage(cur ^ 1, kt + 1);
    bf16x8 af[4], bfr[4];
    #pragma unroll
    for (int m = 0; m < 4; m++)
      af[m] = ld8(&lA[cur][(wr * 64 + m * 16 + lr) * 32 + lg * 8]);
    #pragma unroll
    for (int n = 0; n < 4; n++)
      bfr[n] = ld8(&lB[cur][(wc * 64 + n * 16 + lr) * 32 + lg * 8]);
    __builtin_amdgcn_s_setprio(1);
    #pragma unroll
    for (int m = 0; m < 4; m++)
      #pragma unroll
      for (int n = 0; n < 4; n++)
        acc[m][n] = MFMA(af[m], bfr[n], acc[m][n]);
    __builtin_amdgcn_s_setprio(0);
    asm volatile("s_waitcnt vmcnt(0)" ::: "memory");
    __syncthreads();
    cur ^= 1;
  }

  #pragma unroll
  for (int n = 0; n < 4; n++) {
    const int col = n0 + wc * 64 + n * 16 + lr;
    const float bias = bo[col];
    #pragma unroll
    for (int m = 0; m < 4; m++) {
      const int row = m0 + wr * 64 + m * 16 + lg * 4;
      #pragma unroll
      for (int r = 0; r < 4; r++)
        out[(size_t)(row + r) * R_ + col] = acc[m][n][r] + bias;
    }
  }
}

extern "C" void kernel_launch(void* const* d_in, const int* in_sizes, int n_in,
                              void* d_out, int out_size, void* d_ws, size_t ws_size,
                              hipStream_t stream) {
  const float* resid = (const float*)d_in[0];
  const float* Wqkv  = (const float*)d_in[1];
  const float* bqkv  = (const float*)d_in[2];
  const float* Wo    = (const float*)d_in[3];
  const float* bo    = (const float*)d_in[4];
  float* out = (float*)d_out;

  // workspace carve-up (bf16 buffers), total ~50 MB
  ushort_t* Xb  = (ushort_t*)d_ws;                         // [4096][1024]
  ushort_t* WT  = Xb  + (size_t)N_ * R_;                   // [16][192][1024]
  ushort_t* WoT = WT  + (size_t)H_ * 192 * R_;             // [1024][1024]
  ushort_t* Qd  = WoT + (size_t)R_ * R_;                   // [32][2048][64]
  ushort_t* Kd  = Qd  + (size_t)B_ * H_ * S_ * HD;         // swizzled
  ushort_t* Vtd = Kd  + (size_t)B_ * H_ * S_ * HD;         // [32][64][2048] swizzled
  ushort_t* AOd = Vtd + (size_t)B_ * H_ * S_ * HD;         // [4096][1024]

  k_convert_x<<<dim3(4096), dim3(256), 0, stream>>>(resid, Xb);
  k_transpose<<<dim3(16, 3, 16), dim3(256), 0, stream>>>(Wqkv, WT, 1024, 192);
  k_transpose<<<dim3(16, 16, 1), dim3(256), 0, stream>>>(Wo, WoT, 1024, 1024);
  k_qkv<<<dim3(32, 16), dim3(256), 0, stream>>>(Xb, WT, bqkv, Qd, Kd, Vtd);
  k_attn<<<dim3(16, 32), dim3(256), 0, stream>>>(Qd, Kd, Vtd, AOd);
  k_out<<<dim3(32, 8), dim3(256), 0, stream>>>(AOd, WoT, bo, out);
}